// Round 2
// baseline (888.308 us; speedup 1.0000x reference)
//
#include <hip/hip_runtime.h>
#include <hip/hip_bf16.h>

typedef unsigned short u16;
typedef unsigned int   u32;

using bf16x8 = __attribute__((ext_vector_type(8))) short;
using f32x4  = __attribute__((ext_vector_type(4))) float;

// ---------- constants ----------
#define NB    32      // batch
#define CC    64      // in channels
#define WW_   4096    // input width
#define FF    128     // out channels
#define TAPS  9
#define NFFT  8192
#define KBINS 3597    // half_compressed
#define N2    7194    // compress_fft_size
#define OW    4088    // out width
#define KP    7232    // padded 2*KBINS (mult of 64)
#define MP1   7296    // padded 2*KBINS cols for G1 (mult of 128)
#define SIG1  2048    // N*C
#define SIG2  4096    // N*F

__device__ __forceinline__ u16 f2bf(float f) {
    u32 u = __float_as_uint(f);
    return (u16)((u + 0x7FFFu + ((u >> 16) & 1u)) >> 16);
}
__device__ __forceinline__ float bf2f(u16 h) {
    return __uint_as_float(((u32)h) << 16);
}

// ---------- cast x to bf16 ----------
__global__ __launch_bounds__(256) void cast_x(const float* __restrict__ x,
                                              u16* __restrict__ xb, int n) {
    int stride = gridDim.x * blockDim.x;
    for (int i = blockIdx.x * blockDim.x + threadIdx.x; i < n; i += stride)
        xb[i] = f2bf(x[i]);
}

// ---------- Ttab[m][tau], m=2k(+1): cos / -sin of 2*pi*k*tau/8192 ----------
__global__ __launch_bounds__(256) void gen_ttab(u16* __restrict__ T) {
    int m = blockIdx.x;              // 0..MP1-1
    int k = m >> 1;
    u16* row = T + (size_t)m * WW_;
    for (int tau = threadIdx.x; tau < WW_; tau += 256) {
        float v = 0.f;
        if (k < KBINS) {
            int r = (k * tau) & (NFFT - 1);   // exact integer phase
            float th = (float)r * (6.28318530717958647692f / (float)NFFT);
            float s, c;
            sincosf(th, &s, &c);
            v = (m & 1) ? -s : c;
        }
        row[tau] = f2bf(v);
    }
}

// ---------- Dtab[t][k2]: scaled cos / -sin of 2*pi*k*t/7194 ----------
__global__ __launch_bounds__(256) void gen_dtab(u16* __restrict__ D) {
    int t = blockIdx.x;              // 0..4095
    u16* row = D + (size_t)t * KP;
    for (int k2 = threadIdx.x; k2 < KP; k2 += 256) {
        int k = k2 >> 1;
        float v = 0.f;
        if (k < KBINS) {
            int r = (k * t) % N2;             // exact integer phase
            float th = (float)r * (6.28318530717958647692f / (float)N2);
            float s, c;
            sincosf(th, &s, &c);
            float sc = (k == 0) ? (1.0f / (float)N2) : (2.0f / (float)N2);
            v = (k2 & 1) ? (-s * sc) : (c * sc);
        }
        row[k2] = f2bf(v);
    }
}

// ---------- MFMA GEMM: out[m][n] = sum_k A[m][k]*BT[n][k] ----------
// MODE 0: bf16 out, ldo given.  MODE 1: f32 out (ld OW, col guard) + bias.
template <int MODE>
__global__ __launch_bounds__(256) void gemm_bt(const u16* __restrict__ A,
                                               const u16* __restrict__ B,
                                               int K, void* __restrict__ Out,
                                               int ldo,
                                               const float* __restrict__ bias) {
    __shared__ u16 lA[128 * 64];
    __shared__ u16 lB[128 * 64];
    const int tid  = threadIdx.x;
    const int lane = tid & 63;
    const int wid  = tid >> 6;
    const int wr   = wid >> 1, wc = wid & 1;
    const int tm = blockIdx.x, tn = blockIdx.y;

    f32x4 acc[4][4];
#pragma unroll
    for (int i = 0; i < 4; i++)
#pragma unroll
        for (int j = 0; j < 4; j++) acc[i][j] = (f32x4){0.f, 0.f, 0.f, 0.f};

    const int srow  = tid >> 1;      // 0..127
    const int shalf = tid & 1;       // 0..1
    const u16* gA = A + (size_t)(tm * 128 + srow) * K + shalf * 32;
    const u16* gB = B + (size_t)(tn * 128 + srow) * K + shalf * 32;
    char* lac = (char*)lA;
    char* lbc = (char*)lB;
    const int rowoff = srow * 128;
    const int swz    = (srow & 7) << 4;

    for (int kt = 0; kt < K; kt += 64) {
        // stage A,B tiles (128 x 64 bf16 each), XOR-swizzled rows
#pragma unroll
        for (int i = 0; i < 4; i++) {
            int cb  = shalf * 64 + i * 16;
            int off = rowoff + (cb ^ swz);
            *(bf16x8*)(lac + off) =
                *(const bf16x8*)((const char*)gA + (size_t)kt * 2 + i * 16);
            *(bf16x8*)(lbc + off) =
                *(const bf16x8*)((const char*)gB + (size_t)kt * 2 + i * 16);
        }
        __syncthreads();
#pragma unroll
        for (int kk = 0; kk < 2; kk++) {
            bf16x8 af[4], bfr[4];
#pragma unroll
            for (int m4 = 0; m4 < 4; m4++) {
                int row = wr * 64 + m4 * 16 + (lane & 15);
                int cb  = kk * 64 + ((lane >> 4) << 4);
                af[m4] = *(const bf16x8*)(lac + row * 128 + (cb ^ ((row & 7) << 4)));
            }
#pragma unroll
            for (int n4 = 0; n4 < 4; n4++) {
                int row = wc * 64 + n4 * 16 + (lane & 15);
                int cb  = kk * 64 + ((lane >> 4) << 4);
                bfr[n4] = *(const bf16x8*)(lbc + row * 128 + (cb ^ ((row & 7) << 4)));
            }
#pragma unroll
            for (int m4 = 0; m4 < 4; m4++)
#pragma unroll
                for (int n4 = 0; n4 < 4; n4++)
                    acc[m4][n4] = __builtin_amdgcn_mfma_f32_16x16x32_bf16(
                        af[m4], bfr[n4], acc[m4][n4], 0, 0, 0);
        }
        __syncthreads();
    }

    // epilogue: C/D layout col=lane&15, row=(lane>>4)*4+reg   [m89-verified]
#pragma unroll
    for (int m4 = 0; m4 < 4; m4++) {
#pragma unroll
        for (int n4 = 0; n4 < 4; n4++) {
            int col  = tn * 128 + wc * 64 + n4 * 16 + (lane & 15);
            int row0 = tm * 128 + wr * 64 + m4 * 16 + ((lane >> 4) << 2);
#pragma unroll
            for (int j = 0; j < 4; j++) {
                int grow = row0 + j;
                if (MODE == 0) {
                    ((u16*)Out)[(size_t)grow * ldo + col] = f2bf(acc[m4][n4][j]);
                } else {
                    if (col < OW) {
                        float v = acc[m4][n4][j] + bias[grow & 127];
                        ((float*)Out)[(size_t)grow * OW + col] = v;  // f32 output
                    }
                }
            }
        }
    }
}

// ---------- stepC: spec[n,f,k] = sum_c X[n,c,k]*conj(F[f,c,k]) -> S bf16 ----------
// grid: (113 k-tiles of 32 bins, 8 n-tiles of 4, 4 f-tiles of 32); 256 thr
__global__ __launch_bounds__(256) void step_c(const u16* __restrict__ Xf,
                                              const float* __restrict__ filt,
                                              u16* __restrict__ S) {
    __shared__ float lx[4 * 64 * 64];   // [n'][c][swizzled k2 local]
    const int tid = threadIdx.x;
    const int kt = blockIdx.x, nt = blockIdx.y, ft = blockIdx.z;
    const int k2base = kt * 64;

    {   // stage X slice (bf16 -> f32): rows sig=(nt*4+n')*64+c, cols [k2base,+64)
        int n_ = tid >> 6, c = tid & 63;
        int sig = (nt * 4 + n_) * 64 + c;
        const bf16x8* src = (const bf16x8*)(Xf + (size_t)sig * MP1 + k2base);
        float* dst = lx + tid * 64;
        const int sw = tid & 63;        // == c; bank-conflict swizzle key
#pragma unroll
        for (int i = 0; i < 8; i++) {
            bf16x8 v = src[i];
#pragma unroll
            for (int j = 0; j < 8; j++)
                dst[((i * 8 + j) + sw) & 63] = bf2f((u16)v[j]);
        }
    }
    __syncthreads();

    const int klane = tid & 31, grp = tid >> 5;
    const int k = kt * 32 + klane;
    const bool valid = (k < KBINS);
    float cw[TAPS], sw9[TAPS];
#pragma unroll
    for (int w = 0; w < TAPS; w++) {
        int r = (k * w) & (NFFT - 1);
        float th = (float)r * (6.28318530717958647692f / (float)NFFT);
        float s, c;
        sincosf(th, &s, &c);
        cw[w]  = valid ? c : 0.f;
        sw9[w] = valid ? s : 0.f;
    }

    const int f0 = ft * 32 + grp * 4;
    float aR[4][4] = {}, aI[4][4] = {};
    for (int c = 0; c < CC; c++) {
        float fr[4], fi[4];
#pragma unroll
        for (int j = 0; j < 4; j++) {
            const float* fp = filt + ((size_t)(f0 + j) * CC + c) * TAPS;
            float r = 0.f, im = 0.f;
#pragma unroll
            for (int w = 0; w < TAPS; w++) {
                float fv = fp[w];
                r  += fv * cw[w];    // Re(Y)
                im += fv * sw9[w];   // -Im(Y) = Im(conj Y)
            }
            fr[j] = r;
            fi[j] = im;
        }
#pragma unroll
        for (int n_ = 0; n_ < 4; n_++) {
            int rowb = (n_ * 64 + c) * 64;
            float xr = lx[rowb + ((2 * klane + c) & 63)];
            float xi = lx[rowb + ((2 * klane + 1 + c) & 63)];
#pragma unroll
            for (int j = 0; j < 4; j++) {
                aR[n_][j] += xr * fr[j] - xi * fi[j];
                aI[n_][j] += xr * fi[j] + xi * fr[j];
            }
        }
    }
#pragma unroll
    for (int n_ = 0; n_ < 4; n_++)
#pragma unroll
        for (int j = 0; j < 4; j++) {
            int sig2 = (nt * 4 + n_) * 128 + (f0 + j);
            size_t base = (size_t)sig2 * KP + 2 * k;
            u32 pack = (u32)f2bf(aR[n_][j]) | ((u32)f2bf(aI[n_][j]) << 16);
            *(u32*)(S + base) = pack;
        }
}

// ---------- launch ----------
extern "C" void kernel_launch(void* const* d_in, const int* in_sizes, int n_in,
                              void* d_out, int out_size, void* d_ws, size_t ws_size,
                              hipStream_t stream) {
    (void)in_sizes; (void)n_in; (void)out_size; (void)ws_size;
    const float* x    = (const float*)d_in[0];
    const float* filt = (const float*)d_in[1];
    const float* bias = (const float*)d_in[2];

    char* ws = (char*)d_ws;
    // Ttab (MP1 x 4096 bf16) shares its buffer with Dtab (4096 x KP bf16)
    u16* TT = (u16*)(ws);                  // 59,768,832 B
    u16* XF = (u16*)(ws + 59768832);       // 2048 x 7296 bf16 = 29,884,416
    u16* XB = (u16*)(ws + 89653248);       // 2048 x 4096 bf16 = 16,777,216
    u16* S  = (u16*)(ws + 106430464);      // 4096 x 7232 bf16 = 59,244,544
    // total: 165,675,008 B

    cast_x<<<4096, 256, 0, stream>>>(x, XB, NB * CC * WW_);
    gen_ttab<<<MP1, 256, 0, stream>>>(TT);
    gemm_bt<0><<<dim3(SIG1 / 128, MP1 / 128), 256, 0, stream>>>(
        XB, TT, WW_, XF, MP1, nullptr);
    gen_dtab<<<SIG2, 256, 0, stream>>>(TT);   // overwrites Ttab (dead after G1)
    step_c<<<dim3(113, 8, 4), 256, 0, stream>>>(XF, filt, S);
    gemm_bt<1><<<dim3(SIG2 / 128, SIG2 / 128), 256, 0, stream>>>(
        S, TT, KP, d_out, OW, bias);
}

// Round 3
// 866.031 us; speedup vs baseline: 1.0257x; 1.0257x over previous
//
#include <hip/hip_runtime.h>
#include <hip/hip_bf16.h>

typedef unsigned short u16;
typedef unsigned int   u32;

using bf16x8 = __attribute__((ext_vector_type(8))) short;
using f32x4  = __attribute__((ext_vector_type(4))) float;

// ---------- constants ----------
#define NB    32      // batch
#define CC    64      // in channels
#define WW_   4096    // input width
#define FF    128     // out channels
#define TAPS  9
#define NFFT  8192
#define KBINS 3597    // half_compressed
#define N2    7194    // compress_fft_size
#define OW    4088    // out width
#define KP    7232    // padded 2*KBINS (mult of 64)
#define MP1   7296    // padded 2*KBINS cols for G1 (mult of 128)
#define SIG1  2048    // N*C
#define SIG2  4096    // N*F

__device__ __forceinline__ u16 f2bf(float f) {
    u32 u = __float_as_uint(f);
    return (u16)((u + 0x7FFFu + ((u >> 16) & 1u)) >> 16);
}
__device__ __forceinline__ float bf2f(u16 h) {
    return __uint_as_float(((u32)h) << 16);
}

// async global->LDS, 16B per lane; lds dest must be wave-uniform base
__device__ __forceinline__ void gload16(const void* g, void* l) {
    __builtin_amdgcn_global_load_lds(
        (const __attribute__((address_space(1))) void*)g,
        (__attribute__((address_space(3))) void*)l, 16, 0, 0);
}

// ---------- cast x to bf16 ----------
__global__ __launch_bounds__(256) void cast_x(const float* __restrict__ x,
                                              u16* __restrict__ xb, int n) {
    int stride = gridDim.x * blockDim.x;
    for (int i = blockIdx.x * blockDim.x + threadIdx.x; i < n; i += stride)
        xb[i] = f2bf(x[i]);
}

// ---------- Ttab[m][tau], m=2k(+1): cos / -sin of 2*pi*k*tau/8192 ----------
__global__ __launch_bounds__(256) void gen_ttab(u16* __restrict__ T) {
    int m = blockIdx.x;              // 0..MP1-1
    int k = m >> 1;
    u16* row = T + (size_t)m * WW_;
    for (int tau = threadIdx.x; tau < WW_; tau += 256) {
        float v = 0.f;
        if (k < KBINS) {
            int r = (k * tau) & (NFFT - 1);   // exact integer phase
            float th = (float)r * (6.28318530717958647692f / (float)NFFT);
            float s, c;
            sincosf(th, &s, &c);
            v = (m & 1) ? -s : c;
        }
        row[tau] = f2bf(v);
    }
}

// ---------- Dtab[t][k2]: scaled cos / -sin of 2*pi*k*t/7194 ----------
__global__ __launch_bounds__(256) void gen_dtab(u16* __restrict__ D) {
    int t = blockIdx.x;              // 0..4095
    u16* row = D + (size_t)t * KP;
    for (int k2 = threadIdx.x; k2 < KP; k2 += 256) {
        int k = k2 >> 1;
        float v = 0.f;
        if (k < KBINS) {
            int r = (k * t) % N2;             // exact integer phase
            float th = (float)r * (6.28318530717958647692f / (float)N2);
            float s, c;
            sincosf(th, &s, &c);
            float sc = (k == 0) ? (1.0f / (float)N2) : (2.0f / (float)N2);
            v = (k2 & 1) ? (-s * sc) : (c * sc);
        }
        row[k2] = f2bf(v);
    }
}

// ---------- MFMA GEMM: out[m][n] = sum_k A[m][k]*BT[n][k] ----------
// m97 structure: 128x128 tile, BK=64, global_load_lds(16) staging, linear LDS.
// MODE 0: bf16 out, ldo given.  MODE 1: f32 out (ld OW, col guard) + bias.
template <int MODE>
__global__ __launch_bounds__(256) void gemm_bt(const u16* __restrict__ A,
                                               const u16* __restrict__ B,
                                               int K, void* __restrict__ Out,
                                               int ldo,
                                               const float* __restrict__ bias) {
    __shared__ u16 lA[128 * 64];
    __shared__ u16 lB[128 * 64];
    const int tid  = threadIdx.x;
    const int lane = tid & 63;
    const int wid  = tid >> 6;
    const int wr   = wid >> 1, wc = wid & 1;
    const int tm = blockIdx.x, tn = blockIdx.y;

    f32x4 acc[4][4];
#pragma unroll
    for (int i = 0; i < 4; i++)
#pragma unroll
        for (int j = 0; j < 4; j++) acc[i][j] = (f32x4){0.f, 0.f, 0.f, 0.f};

    // staging: lane covers LDS bytes [lane*16, +16) of each 8-row stripe.
    // stripe j of wave wid = tile rows wid*32 + j*8 .. +7, cols 0..63.
    // per-lane global addr: row += lane>>3, col = (lane&7)*8 elems.
    const int lrow = wid * 32 + (lane >> 3);
    const int lcol = (lane & 7) * 8;
    const u16* gA = A + (size_t)(tm * 128 + lrow) * K + lcol;
    const u16* gB = B + (size_t)(tn * 128 + lrow) * K + lcol;
    char* lac = (char*)lA;
    char* lbc = (char*)lB;

    for (int kt = 0; kt < K; kt += 64) {
#pragma unroll
        for (int j = 0; j < 4; j++) {
            // LDS base: depends on wid/j only -> wave-uniform
            int lbase = (wid * 32 + j * 8) * 128;
            gload16(gA + (size_t)(j * 8) * K + kt, lac + lbase);
            gload16(gB + (size_t)(j * 8) * K + kt, lbc + lbase);
        }
        __syncthreads();   // compiler drains vmcnt before barrier
#pragma unroll
        for (int kk = 0; kk < 2; kk++) {
            bf16x8 af[4], bfr[4];
#pragma unroll
            for (int m4 = 0; m4 < 4; m4++) {
                int row = wr * 64 + m4 * 16 + (lane & 15);
                af[m4] = *(const bf16x8*)(lac + row * 128 + kk * 64 +
                                          ((lane >> 4) << 4));
            }
#pragma unroll
            for (int n4 = 0; n4 < 4; n4++) {
                int row = wc * 64 + n4 * 16 + (lane & 15);
                bfr[n4] = *(const bf16x8*)(lbc + row * 128 + kk * 64 +
                                           ((lane >> 4) << 4));
            }
#pragma unroll
            for (int m4 = 0; m4 < 4; m4++)
#pragma unroll
                for (int n4 = 0; n4 < 4; n4++)
                    acc[m4][n4] = __builtin_amdgcn_mfma_f32_16x16x32_bf16(
                        af[m4], bfr[n4], acc[m4][n4], 0, 0, 0);
        }
        __syncthreads();
    }

    // epilogue: C/D layout col=lane&15, row=(lane>>4)*4+reg   [m89-verified]
#pragma unroll
    for (int m4 = 0; m4 < 4; m4++) {
#pragma unroll
        for (int n4 = 0; n4 < 4; n4++) {
            int col  = tn * 128 + wc * 64 + n4 * 16 + (lane & 15);
            int row0 = tm * 128 + wr * 64 + m4 * 16 + ((lane >> 4) << 2);
#pragma unroll
            for (int j = 0; j < 4; j++) {
                int grow = row0 + j;
                if (MODE == 0) {
                    ((u16*)Out)[(size_t)grow * ldo + col] = f2bf(acc[m4][n4][j]);
                } else {
                    if (col < OW) {
                        float v = acc[m4][n4][j] + bias[grow & 127];
                        ((float*)Out)[(size_t)grow * OW + col] = v;  // f32 output
                    }
                }
            }
        }
    }
}

// ---------- stepC: spec[n,f,k] = sum_c X[n,c,k]*conj(F[f,c,k]) -> S bf16 ----------
// grid: (113 k-tiles of 32 bins, 8 n-tiles of 4, 4 f-tiles of 32); 256 thr
__global__ __launch_bounds__(256) void step_c(const u16* __restrict__ Xf,
                                              const float* __restrict__ filt,
                                              u16* __restrict__ S) {
    __shared__ float lx[4 * 64 * 64];   // [n'][c][swizzled k2 local]
    const int tid = threadIdx.x;
    const int kt = blockIdx.x, nt = blockIdx.y, ft = blockIdx.z;
    const int k2base = kt * 64;

    {   // stage X slice (bf16 -> f32): rows sig=(nt*4+n')*64+c, cols [k2base,+64)
        int n_ = tid >> 6, c = tid & 63;
        int sig = (nt * 4 + n_) * 64 + c;
        const bf16x8* src = (const bf16x8*)(Xf + (size_t)sig * MP1 + k2base);
        float* dst = lx + tid * 64;
        const int sw = tid & 63;        // == c; bank-conflict swizzle key
#pragma unroll
        for (int i = 0; i < 8; i++) {
            bf16x8 v = src[i];
#pragma unroll
            for (int j = 0; j < 8; j++)
                dst[((i * 8 + j) + sw) & 63] = bf2f((u16)v[j]);
        }
    }
    __syncthreads();

    const int klane = tid & 31, grp = tid >> 5;
    const int k = kt * 32 + klane;
    const bool valid = (k < KBINS);
    float cw[TAPS], sw9[TAPS];
#pragma unroll
    for (int w = 0; w < TAPS; w++) {
        int r = (k * w) & (NFFT - 1);
        float th = (float)r * (6.28318530717958647692f / (float)NFFT);
        float s, c;
        sincosf(th, &s, &c);
        cw[w]  = valid ? c : 0.f;
        sw9[w] = valid ? s : 0.f;
    }

    const int f0 = ft * 32 + grp * 4;
    float aR[4][4] = {}, aI[4][4] = {};
    for (int c = 0; c < CC; c++) {
        float fr[4], fi[4];
#pragma unroll
        for (int j = 0; j < 4; j++) {
            const float* fp = filt + ((size_t)(f0 + j) * CC + c) * TAPS;
            float r = 0.f, im = 0.f;
#pragma unroll
            for (int w = 0; w < TAPS; w++) {
                float fv = fp[w];
                r  += fv * cw[w];    // Re(Y)
                im += fv * sw9[w];   // -Im(Y) = Im(conj Y)
            }
            fr[j] = r;
            fi[j] = im;
        }
#pragma unroll
        for (int n_ = 0; n_ < 4; n_++) {
            int rowb = (n_ * 64 + c) * 64;
            float xr = lx[rowb + ((2 * klane + c) & 63)];
            float xi = lx[rowb + ((2 * klane + 1 + c) & 63)];
#pragma unroll
            for (int j = 0; j < 4; j++) {
                aR[n_][j] += xr * fr[j] - xi * fi[j];
                aI[n_][j] += xr * fi[j] + xi * fr[j];
            }
        }
    }
#pragma unroll
    for (int n_ = 0; n_ < 4; n_++)
#pragma unroll
        for (int j = 0; j < 4; j++) {
            int sig2 = (nt * 4 + n_) * 128 + (f0 + j);
            size_t base = (size_t)sig2 * KP + 2 * k;
            u32 pack = (u32)f2bf(aR[n_][j]) | ((u32)f2bf(aI[n_][j]) << 16);
            *(u32*)(S + base) = pack;
        }
}

// ---------- launch ----------
extern "C" void kernel_launch(void* const* d_in, const int* in_sizes, int n_in,
                              void* d_out, int out_size, void* d_ws, size_t ws_size,
                              hipStream_t stream) {
    (void)in_sizes; (void)n_in; (void)out_size; (void)ws_size;
    const float* x    = (const float*)d_in[0];
    const float* filt = (const float*)d_in[1];
    const float* bias = (const float*)d_in[2];

    char* ws = (char*)d_ws;
    // Ttab (MP1 x 4096 bf16) shares its buffer with Dtab (4096 x KP bf16)
    u16* TT = (u16*)(ws);                  // 59,768,832 B
    u16* XF = (u16*)(ws + 59768832);       // 2048 x 7296 bf16 = 29,884,416
    u16* XB = (u16*)(ws + 89653248);       // 2048 x 4096 bf16 = 16,777,216
    u16* S  = (u16*)(ws + 106430464);      // 4096 x 7232 bf16 = 59,244,544
    // total: 165,675,008 B

    cast_x<<<4096, 256, 0, stream>>>(x, XB, NB * CC * WW_);
    gen_ttab<<<MP1, 256, 0, stream>>>(TT);
    gemm_bt<0><<<dim3(SIG1 / 128, MP1 / 128), 256, 0, stream>>>(
        XB, TT, WW_, XF, MP1, nullptr);
    gen_dtab<<<SIG2, 256, 0, stream>>>(TT);   // overwrites Ttab (dead after G1)
    step_c<<<dim3(113, 8, 4), 256, 0, stream>>>(XF, filt, S);
    gemm_bt<1><<<dim3(SIG2 / 128, SIG2 / 128), 256, 0, stream>>>(
        S, TT, KP, d_out, OW, bias);
}

// Round 4
// 682.580 us; speedup vs baseline: 1.3014x; 1.2688x over previous
//
#include <hip/hip_runtime.h>
#include <hip/hip_bf16.h>

typedef unsigned short u16;
typedef unsigned int   u32;

using bf16x8 = __attribute__((ext_vector_type(8))) short;
using f32x4  = __attribute__((ext_vector_type(4))) float;

// ---------- constants ----------
#define NB    32      // batch
#define CC    64      // in channels
#define WW_   4096    // input width
#define FF    128     // out channels
#define TAPS  9
#define NFFT  8192
#define KBINS 3597    // half_compressed
#define N2    7194    // compress_fft_size
#define OW    4088    // out width
#define KP    7232    // padded 2*KBINS (mult of 64)
#define MP1   7424    // padded 2*KBINS cols for G1 (mult of 256)
#define SIG1  2048    // N*C
#define SIG2  4096    // N*F

__device__ __forceinline__ u16 f2bf(float f) {
    u32 u = __float_as_uint(f);
    return (u16)((u + 0x7FFFu + ((u >> 16) & 1u)) >> 16);
}
__device__ __forceinline__ float bf2f(u16 h) {
    return __uint_as_float(((u32)h) << 16);
}

// async global->LDS, 16B per lane; lds dest is wave-uniform base + lane*16
__device__ __forceinline__ void gload16(const void* g, void* l) {
    __builtin_amdgcn_global_load_lds(
        (const __attribute__((address_space(1))) void*)g,
        (__attribute__((address_space(3))) void*)l, 16, 0, 0);
}

// ---------- cast x to bf16 ----------
__global__ __launch_bounds__(256) void cast_x(const float* __restrict__ x,
                                              u16* __restrict__ xb, int n) {
    int stride = gridDim.x * blockDim.x;
    for (int i = blockIdx.x * blockDim.x + threadIdx.x; i < n; i += stride)
        xb[i] = f2bf(x[i]);
}

// ---------- Ttab[m][tau], m=2k(+1): cos / -sin of 2*pi*k*tau/8192 ----------
__global__ __launch_bounds__(256) void gen_ttab(u16* __restrict__ T) {
    int m = blockIdx.x;              // 0..MP1-1
    int k = m >> 1;
    u16* row = T + (size_t)m * WW_;
    for (int tau = threadIdx.x; tau < WW_; tau += 256) {
        float v = 0.f;
        if (k < KBINS && m < 2 * KBINS) {
            int r = (k * tau) & (NFFT - 1);   // exact integer phase
            float th = (float)r * (6.28318530717958647692f / (float)NFFT);
            float s, c;
            sincosf(th, &s, &c);
            v = (m & 1) ? -s : c;
        }
        row[tau] = f2bf(v);
    }
}

// ---------- Dtab[t][k2]: scaled cos / -sin of 2*pi*k*t/7194 ----------
__global__ __launch_bounds__(256) void gen_dtab(u16* __restrict__ D) {
    int t = blockIdx.x;              // 0..4095
    u16* row = D + (size_t)t * KP;
    for (int k2 = threadIdx.x; k2 < KP; k2 += 256) {
        int k = k2 >> 1;
        float v = 0.f;
        if (k < KBINS) {
            int r = (k * t) % N2;             // exact integer phase
            float th = (float)r * (6.28318530717958647692f / (float)N2);
            float s, c;
            sincosf(th, &s, &c);
            float sc = (k == 0) ? (1.0f / (float)N2) : (2.0f / (float)N2);
            v = (k2 & 1) ? (-s * sc) : (c * sc);
        }
        row[k2] = f2bf(v);
    }
}

// ============ 256x256 8-phase MFMA GEMM:  out[m][n] = sum_k A[m][k]*BT[n][k]
// 512 thr = 8 waves (2M x 4N); BK=64; LDS 128KB double-buffered.
// Staging ledger (per K-tile t, cur=t&1, nxt=cur^1):
//   p0: read A-mh0+B-nh0; stage B0(t+1)->nxt     (B region of nxt idle)
//   p1: read B-nh1;       stage B1(t+1)->nxt
//   p2: read A-mh1;       (no stage)
//   p3: (no read);        stage A0(t+2)+A1(t+2)->cur (A consumed end p2)
//   end: vmcnt(4) keeps A(t+2) in flight; tile t+1 fully landed.
// LDS read swizzle: col16 ^= (row&7); staging pre-swizzles global source.
#define MFMA_Q(AS, BS, MH, NH)                                              \
    __builtin_amdgcn_s_setprio(1);                                          \
    _Pragma("unroll")                                                       \
    for (int kk = 0; kk < 2; kk++)                                          \
        _Pragma("unroll")                                                   \
        for (int m4 = 0; m4 < 4; m4++)                                      \
            _Pragma("unroll")                                               \
            for (int n2 = 0; n2 < 2; n2++)                                  \
                acc[(MH)*4 + m4][(NH)*2 + n2] =                             \
                    __builtin_amdgcn_mfma_f32_16x16x32_bf16(                \
                        AS[m4][kk], BS[n2][kk],                             \
                        acc[(MH)*4 + m4][(NH)*2 + n2], 0, 0, 0);            \
    __builtin_amdgcn_s_setprio(0);

#define LOAD_A(AS, MH, BUF)                                                 \
    _Pragma("unroll")                                                       \
    for (int m4 = 0; m4 < 4; m4++)                                          \
        _Pragma("unroll")                                                   \
        for (int kk = 0; kk < 2; kk++) {                                    \
            int row_ = wr * 128 + (MH)*64 + m4 * 16 + fr;                   \
            AS[m4][kk] = *(const bf16x8*)(smem + (BUF)*32768 +              \
                          row_ * 128 + ((kk * 64 + hk) ^ askew));           \
        }

#define LOAD_B(BS, NH, BUF)                                                 \
    _Pragma("unroll")                                                       \
    for (int n2 = 0; n2 < 2; n2++)                                          \
        _Pragma("unroll")                                                   \
        for (int kk = 0; kk < 2; kk++) {                                    \
            int row_ = wc * 64 + (NH)*32 + n2 * 16 + fr;                    \
            BS[n2][kk] = *(const bf16x8*)(smem + 65536 + (BUF)*32768 +      \
                          row_ * 128 + ((kk * 64 + hk) ^ askew));           \
        }

// stage half-tile R (0:A rows0-127,1:A rows128-255,2:B0,3:B1) of K-tile Q
#define STAGE(Q, R, BUF)                                                    \
    {                                                                       \
        const u16* g_ = ((R) < 2) ? gA : gB;                                \
        size_t ro_ = (size_t)((R)&1) * 128 * K;                             \
        int lb_ = (((R) < 2) ? 0 : 65536) + (BUF)*32768 +                   \
                  (((R)&1) * 128 + wid * 16) * 128;                         \
        gload16(g_ + ro_ + (Q)*64, smem + lb_);                             \
        gload16(g_ + ro_ + (size_t)8 * K + (Q)*64, smem + lb_ + 1024);      \
    }

#define BAR() __builtin_amdgcn_s_barrier()

template <int MODE>
__global__ __launch_bounds__(512, 1) void gemm256(const u16* __restrict__ A,
                                                  const u16* __restrict__ B,
                                                  int K, int gridN,
                                                  void* __restrict__ Out,
                                                  int ldo,
                                                  const float* __restrict__ bias) {
    extern __shared__ char smem[];   // [A b0|A b1|B b0|B b1] x 32KB
    const int tid = threadIdx.x;
    const int lane = tid & 63, wid = tid >> 6;
    const int wr = wid >> 2, wc = wid & 3;
    const int fr = lane & 15;
    const int hk = (lane >> 4) << 4;
    const int askew = (fr & 7) << 4;

    // bijective XCD swizzle (grid % 8 == 0)
    const int nwg = (int)gridDim.x, cpx = nwg >> 3;
    const int bid = (int)blockIdx.x;
    const int wg = (bid & 7) * cpx + (bid >> 3);
    const int tm = wg / gridN, tn = wg % gridN;
    const int NT = K >> 6;

    f32x4 acc[8][4];
#pragma unroll
    for (int i = 0; i < 8; i++)
#pragma unroll
        for (int j = 0; j < 4; j++) acc[i][j] = (f32x4){0.f, 0.f, 0.f, 0.f};

    // per-lane staging source (pre-swizzled: col16 ^= srow)
    const int srow = lane >> 3;
    const int scol = ((lane & 7) ^ srow) * 8;
    const u16* gA = A + (size_t)(tm * 256 + wid * 16 + srow) * K + scol;
    const u16* gB = B + (size_t)(tn * 256 + wid * 16 + srow) * K + scol;

    // prologue: tile0 (buf0) + A-halves of tile1 (buf1); vmcnt leaves A(1)
    STAGE(0, 0, 0) STAGE(0, 1, 0) STAGE(0, 2, 0) STAGE(0, 3, 0)
    STAGE(1, 0, 1) STAGE(1, 1, 1)
    asm volatile("s_waitcnt vmcnt(4)" ::: "memory");
    BAR();

    bf16x8 as[4][2], bs0[2][2], bs1[2][2];
    for (int t = 0; t < NT; ++t) {
        const int cur = t & 1, nxt = cur ^ 1;
        // ---- p0
        LOAD_A(as, 0, cur)
        LOAD_B(bs0, 0, cur)
        if (t + 1 < NT) STAGE(t + 1, 2, nxt)
        BAR();
        MFMA_Q(as, bs0, 0, 0)
        BAR();
        // ---- p1
        LOAD_B(bs1, 1, cur)
        if (t + 1 < NT) STAGE(t + 1, 3, nxt)
        BAR();
        MFMA_Q(as, bs1, 0, 1)
        BAR();
        // ---- p2
        LOAD_A(as, 1, cur)
        BAR();
        MFMA_Q(as, bs1, 1, 1)
        BAR();
        // ---- p3
        if (t + 2 < NT) { STAGE(t + 2, 0, cur) STAGE(t + 2, 1, cur) }
        BAR();
        MFMA_Q(as, bs0, 1, 0)
        if (t <= NT - 3) {
            asm volatile("s_waitcnt vmcnt(4)" ::: "memory");
        } else if (t == NT - 2) {
            asm volatile("s_waitcnt vmcnt(0)" ::: "memory");
        }
        BAR();
    }

    // epilogue: C/D frag layout col=lane&15, row=(lane>>4)*4+j  [m89]
#pragma unroll
    for (int m = 0; m < 8; m++) {
#pragma unroll
        for (int n = 0; n < 4; n++) {
            int col  = tn * 256 + wc * 64 + n * 16 + fr;
            int row0 = tm * 256 + wr * 128 + m * 16 + ((lane >> 4) << 2);
#pragma unroll
            for (int j = 0; j < 4; j++) {
                int grow = row0 + j;
                if (MODE == 0) {
                    ((u16*)Out)[(size_t)grow * ldo + col] = f2bf(acc[m][n][j]);
                } else {
                    if (col < OW) {
                        ((float*)Out)[(size_t)grow * OW + col] =
                            acc[m][n][j] + bias[grow & 127];
                    }
                }
            }
        }
    }
}

// ---------- stepC: spec[n,f,k] = sum_c X[n,c,k]*conj(F[f,c,k]) -> S bf16 ----
// grid: (113 k-tiles of 32 bins, 8 n-tiles of 4, 4 f-tiles of 32); 256 thr
__global__ __launch_bounds__(256) void step_c(const u16* __restrict__ Xf,
                                              const float* __restrict__ filt,
                                              u16* __restrict__ S) {
    __shared__ float lx[4 * 64 * 64];   // [n'][c][swizzled k2 local]
    const int tid = threadIdx.x;
    const int kt = blockIdx.x, nt = blockIdx.y, ft = blockIdx.z;
    const int k2base = kt * 64;

    {   // stage X slice (bf16 -> f32)
        int n_ = tid >> 6, c = tid & 63;
        int sig = (nt * 4 + n_) * 64 + c;
        const bf16x8* src = (const bf16x8*)(Xf + (size_t)sig * MP1 + k2base);
        float* dst = lx + tid * 64;
        const int sw = tid & 63;
#pragma unroll
        for (int i = 0; i < 8; i++) {
            bf16x8 v = src[i];
#pragma unroll
            for (int j = 0; j < 8; j++)
                dst[((i * 8 + j) + sw) & 63] = bf2f((u16)v[j]);
        }
    }
    __syncthreads();

    const int klane = tid & 31, grp = tid >> 5;
    const int k = kt * 32 + klane;
    const bool valid = (k < KBINS);
    float cw[TAPS], sw9[TAPS];
#pragma unroll
    for (int w = 0; w < TAPS; w++) {
        int r = (k * w) & (NFFT - 1);
        float th = (float)r * (6.28318530717958647692f / (float)NFFT);
        float s, c;
        sincosf(th, &s, &c);
        cw[w]  = valid ? c : 0.f;
        sw9[w] = valid ? s : 0.f;
    }

    const int f0 = ft * 32 + grp * 4;
    float aR[4][4] = {}, aI[4][4] = {};
    for (int c = 0; c < CC; c++) {
        float fr4[4], fi4[4];
#pragma unroll
        for (int j = 0; j < 4; j++) {
            const float* fp = filt + ((size_t)(f0 + j) * CC + c) * TAPS;
            float r = 0.f, im = 0.f;
#pragma unroll
            for (int w = 0; w < TAPS; w++) {
                float fv = fp[w];
                r  += fv * cw[w];
                im += fv * sw9[w];
            }
            fr4[j] = r;
            fi4[j] = im;
        }
#pragma unroll
        for (int n_ = 0; n_ < 4; n_++) {
            int rowb = (n_ * 64 + c) * 64;
            float xr = lx[rowb + ((2 * klane + c) & 63)];
            float xi = lx[rowb + ((2 * klane + 1 + c) & 63)];
#pragma unroll
            for (int j = 0; j < 4; j++) {
                aR[n_][j] += xr * fr4[j] - xi * fi4[j];
                aI[n_][j] += xr * fi4[j] + xi * fr4[j];
            }
        }
    }
#pragma unroll
    for (int n_ = 0; n_ < 4; n_++)
#pragma unroll
        for (int j = 0; j < 4; j++) {
            int sig2 = (nt * 4 + n_) * 128 + (f0 + j);
            size_t base = (size_t)sig2 * KP + 2 * k;
            u32 pack = (u32)f2bf(aR[n_][j]) | ((u32)f2bf(aI[n_][j]) << 16);
            *(u32*)(S + base) = pack;
        }
}

// ---------- launch ----------
extern "C" void kernel_launch(void* const* d_in, const int* in_sizes, int n_in,
                              void* d_out, int out_size, void* d_ws, size_t ws_size,
                              hipStream_t stream) {
    (void)in_sizes; (void)n_in; (void)out_size; (void)ws_size;
    const float* x    = (const float*)d_in[0];
    const float* filt = (const float*)d_in[1];
    const float* bias = (const float*)d_in[2];

    char* ws = (char*)d_ws;
    // TT holds Ttab (7424x4096 bf16) then is reused for Dtab (4096x7232 bf16)
    u16* TT = (u16*)(ws);                  // 60,817,408 B
    u16* XF = (u16*)(ws + 60817408);       // 2048 x 7424 bf16 = 30,408,704
    u16* XB = (u16*)(ws + 91226112);       // 2048 x 4096 bf16 = 16,777,216
    u16* S  = (u16*)(ws + 108003328);      // 4096 x 7232 bf16 = 59,244,544
    // total: 167,247,872 B

    hipFuncSetAttribute(reinterpret_cast<const void*>(gemm256<0>),
                        hipFuncAttributeMaxDynamicSharedMemorySize, 131072);
    hipFuncSetAttribute(reinterpret_cast<const void*>(gemm256<1>),
                        hipFuncAttributeMaxDynamicSharedMemorySize, 131072);

    cast_x<<<4096, 256, 0, stream>>>(x, XB, NB * CC * WW_);
    gen_ttab<<<MP1, 256, 0, stream>>>(TT);
    gemm256<0><<<8 * (MP1 / 256), 512, 131072, stream>>>(
        XB, TT, WW_, MP1 / 256, XF, MP1, nullptr);
    gen_dtab<<<SIG2, 256, 0, stream>>>(TT);   // overwrites Ttab (dead after G1)
    step_c<<<dim3(KP / 64, 8, 4), 256, 0, stream>>>(XF, filt, S);
    gemm256<1><<<16 * 16, 512, 131072, stream>>>(
        S, TT, KP, 16, d_out, OW, bias);
}

// Round 6
// 457.913 us; speedup vs baseline: 1.9399x; 1.4906x over previous
//
#include <hip/hip_runtime.h>
#include <hip/hip_bf16.h>

typedef unsigned short u16;
typedef unsigned int   u32;

using bf16x8 = __attribute__((ext_vector_type(8))) short;
using f32x4  = __attribute__((ext_vector_type(4))) float;

// ---------- constants ----------
#define NB    32      // batch
#define CC    64      // in channels
#define WW_   4096    // input width
#define FF    128     // out channels
#define TAPS  9
#define NFFT  8192
#define KBINS 3597    // half_compressed
#define KB2   3616    // bins padded to 113*32 (PH table size)
#define N2    7194    // compress_fft_size
#define OW    4088    // out width
#define KP    7232    // padded 2*KBINS (mult of 64)
#define MP1   7424    // padded 2*KBINS cols for G1 (mult of 256)
#define SIG1  2048    // N*C
#define SIG2  4096    // N*F

__device__ __forceinline__ u16 f2bf(float f) {
    u32 u = __float_as_uint(f);
    return (u16)((u + 0x7FFFu + ((u >> 16) & 1u)) >> 16);
}
__device__ __forceinline__ float bf2f(u16 h) {
    return __uint_as_float(((u32)h) << 16);
}

// async global->LDS, 16B per lane; lds dest is wave-uniform base + lane*16
__device__ __forceinline__ void gload16(const void* g, void* l) {
    __builtin_amdgcn_global_load_lds(
        (const __attribute__((address_space(1))) void*)g,
        (__attribute__((address_space(3))) void*)l, 16, 0, 0);
}

// ---------- cast x to bf16 ----------
__global__ __launch_bounds__(256) void cast_x(const float* __restrict__ x,
                                              u16* __restrict__ xb, int n) {
    int stride = gridDim.x * blockDim.x;
    for (int i = blockIdx.x * blockDim.x + threadIdx.x; i < n; i += stride)
        xb[i] = f2bf(x[i]);
}

// ---------- Ttab[m][tau], m=2k(+1): cos / -sin of 2*pi*k*tau/8192 ----------
__global__ __launch_bounds__(256) void gen_ttab(u16* __restrict__ T) {
    int m = blockIdx.x;              // 0..MP1-1
    int k = m >> 1;
    u16* row = T + (size_t)m * WW_;
    for (int tau = threadIdx.x; tau < WW_; tau += 256) {
        float v = 0.f;
        if (k < KBINS && m < 2 * KBINS) {
            int r = (k * tau) & (NFFT - 1);   // exact integer phase
            float th = (float)r * (6.28318530717958647692f / (float)NFFT);
            float s, c;
            sincosf(th, &s, &c);
            v = (m & 1) ? -s : c;
        }
        row[tau] = f2bf(v);
    }
}

// ---------- Dtab[t][k2]: scaled cos / -sin of 2*pi*k*t/7194 ----------
__global__ __launch_bounds__(256) void gen_dtab(u16* __restrict__ D) {
    int t = blockIdx.x;              // 0..4095
    u16* row = D + (size_t)t * KP;
    for (int k2 = threadIdx.x; k2 < KP; k2 += 256) {
        int k = k2 >> 1;
        float v = 0.f;
        if (k < KBINS) {
            int r = (k * t) % N2;             // exact integer phase
            float th = (float)r * (6.28318530717958647692f / (float)N2);
            float s, c;
            sincosf(th, &s, &c);
            float sc = (k == 0) ? (1.0f / (float)N2) : (2.0f / (float)N2);
            v = (k2 & 1) ? (-s * sc) : (c * sc);
        }
        row[k2] = f2bf(v);
    }
}

// ---------- PH[w][b]: (cos,sin) of 2*pi*b*w/8192; 0 for b>=KBINS ----------
__global__ __launch_bounds__(256) void gen_ph(float2* __restrict__ PH) {
    int idx = blockIdx.x * 256 + threadIdx.x;
    if (idx >= TAPS * KB2) return;
    int w = idx / KB2, b = idx % KB2;
    float2 v = {0.f, 0.f};
    if (b < KBINS) {
        int r = (b * w) & (NFFT - 1);
        float th = (float)r * (6.28318530717958647692f / (float)NFFT);
        sincosf(th, &v.y, &v.x);
    }
    PH[idx] = v;
}

// ---------- filt2[f][w*64+c] = bf16(filt[f][c][w]) ----------
__global__ __launch_bounds__(256) void gen_filt2(const float* __restrict__ filt,
                                                 u16* __restrict__ F2) {
    int idx = blockIdx.x * 256 + threadIdx.x;
    if (idx >= FF * 576) return;
    int f = idx / 576, wc = idx % 576;
    int w = wc >> 6, c = wc & 63;
    F2[idx] = f2bf(filt[((size_t)f * CC + c) * TAPS + w]);
}

// ============ 256x256 8-phase MFMA GEMM:  out[m][n] = sum_k A[m][k]*BT[n][k]
#define MFMA_Q(AS, BS, MH, NH)                                              \
    __builtin_amdgcn_s_setprio(1);                                          \
    _Pragma("unroll")                                                       \
    for (int kk = 0; kk < 2; kk++)                                          \
        _Pragma("unroll")                                                   \
        for (int m4 = 0; m4 < 4; m4++)                                      \
            _Pragma("unroll")                                               \
            for (int n2 = 0; n2 < 2; n2++)                                  \
                acc[(MH)*4 + m4][(NH)*2 + n2] =                             \
                    __builtin_amdgcn_mfma_f32_16x16x32_bf16(                \
                        AS[m4][kk], BS[n2][kk],                             \
                        acc[(MH)*4 + m4][(NH)*2 + n2], 0, 0, 0);            \
    __builtin_amdgcn_s_setprio(0);

#define LOAD_A(AS, MH, BUF)                                                 \
    _Pragma("unroll")                                                       \
    for (int m4 = 0; m4 < 4; m4++)                                          \
        _Pragma("unroll")                                                   \
        for (int kk = 0; kk < 2; kk++) {                                    \
            int row_ = wr * 128 + (MH)*64 + m4 * 16 + fr;                   \
            AS[m4][kk] = *(const bf16x8*)(smem + (BUF)*32768 +              \
                          row_ * 128 + ((kk * 64 + hk) ^ askew));           \
        }

#define LOAD_B(BS, NH, BUF)                                                 \
    _Pragma("unroll")                                                       \
    for (int n2 = 0; n2 < 2; n2++)                                          \
        _Pragma("unroll")                                                   \
        for (int kk = 0; kk < 2; kk++) {                                    \
            int row_ = wc * 64 + (NH)*32 + n2 * 16 + fr;                    \
            BS[n2][kk] = *(const bf16x8*)(smem + 65536 + (BUF)*32768 +      \
                          row_ * 128 + ((kk * 64 + hk) ^ askew));           \
        }

#define STAGE(Q, R, BUF)                                                    \
    {                                                                       \
        const u16* g_ = ((R) < 2) ? gA : gB;                                \
        size_t ro_ = (size_t)((R)&1) * 128 * K;                             \
        int lb_ = (((R) < 2) ? 0 : 65536) + (BUF)*32768 +                   \
                  (((R)&1) * 128 + wid * 16) * 128;                         \
        gload16(g_ + ro_ + (Q)*64, smem + lb_);                             \
        gload16(g_ + ro_ + (size_t)8 * K + (Q)*64, smem + lb_ + 1024);      \
    }

#define BAR() __builtin_amdgcn_s_barrier()

template <int MODE>
__global__ __launch_bounds__(512, 1) void gemm256(const u16* __restrict__ A,
                                                  const u16* __restrict__ B,
                                                  int K, int gridN,
                                                  void* __restrict__ Out,
                                                  int ldo,
                                                  const float* __restrict__ bias) {
    extern __shared__ char smem[];   // [A b0|A b1|B b0|B b1] x 32KB
    const int tid = threadIdx.x;
    const int lane = tid & 63, wid = tid >> 6;
    const int wr = wid >> 2, wc = wid & 3;
    const int fr = lane & 15;
    const int hk = (lane >> 4) << 4;
    const int askew = (fr & 7) << 4;

    const int nwg = (int)gridDim.x, cpx = nwg >> 3;
    const int bid = (int)blockIdx.x;
    const int wg = (bid & 7) * cpx + (bid >> 3);
    const int tm = wg / gridN, tn = wg % gridN;
    const int NT = K >> 6;

    f32x4 acc[8][4];
#pragma unroll
    for (int i = 0; i < 8; i++)
#pragma unroll
        for (int j = 0; j < 4; j++) acc[i][j] = (f32x4){0.f, 0.f, 0.f, 0.f};

    const int srow = lane >> 3;
    const int scol = ((lane & 7) ^ srow) * 8;
    const u16* gA = A + (size_t)(tm * 256 + wid * 16 + srow) * K + scol;
    const u16* gB = B + (size_t)(tn * 256 + wid * 16 + srow) * K + scol;

    STAGE(0, 0, 0) STAGE(0, 1, 0) STAGE(0, 2, 0) STAGE(0, 3, 0)
    STAGE(1, 0, 1) STAGE(1, 1, 1)
    asm volatile("s_waitcnt vmcnt(4)" ::: "memory");
    BAR();

    bf16x8 as[4][2], bs0[2][2], bs1[2][2];
    for (int t = 0; t < NT; ++t) {
        const int cur = t & 1, nxt = cur ^ 1;
        LOAD_A(as, 0, cur)
        LOAD_B(bs0, 0, cur)
        if (t + 1 < NT) STAGE(t + 1, 2, nxt)
        BAR();
        MFMA_Q(as, bs0, 0, 0)
        BAR();
        LOAD_B(bs1, 1, cur)
        if (t + 1 < NT) STAGE(t + 1, 3, nxt)
        BAR();
        MFMA_Q(as, bs1, 0, 1)
        BAR();
        LOAD_A(as, 1, cur)
        BAR();
        MFMA_Q(as, bs1, 1, 1)
        BAR();
        if (t + 2 < NT) { STAGE(t + 2, 0, cur) STAGE(t + 2, 1, cur) }
        BAR();
        MFMA_Q(as, bs0, 1, 0)
        if (t <= NT - 3) {
            asm volatile("s_waitcnt vmcnt(4)" ::: "memory");
        } else if (t == NT - 2) {
            asm volatile("s_waitcnt vmcnt(0)" ::: "memory");
        }
        BAR();
    }

#pragma unroll
    for (int m = 0; m < 8; m++) {
#pragma unroll
        for (int n = 0; n < 4; n++) {
            int col  = tn * 256 + wc * 64 + n * 16 + fr;
            int row0 = tm * 256 + wr * 128 + m * 16 + ((lane >> 4) << 2);
#pragma unroll
            for (int j = 0; j < 4; j++) {
                int grow = row0 + j;
                if (MODE == 0) {
                    ((u16*)Out)[(size_t)grow * ldo + col] = f2bf(acc[m][n][j]);
                } else {
                    if (col < OW) {
                        ((float*)Out)[(size_t)grow * OW + col] =
                            acc[m][n][j] + bias[grow & 127];
                    }
                }
            }
        }
    }
}

// ============ step_c2: spectral contraction as one MFMA GEMM over (c,w) ====
// spec[n,f,k] = sum_{c,w} filt[f,c,w] * (X[n,c,k] * e^{i*2pi*k*w/8192})
// A = filt2[f][w*64+c] (128x576 bf16); B = Z tile built in LDS per K-step
// (step t == tap w=t). Block: (kt: 64 k2-cols = 32 bins, n). 256 thr, 4 waves.
#define ZBUILD(T, BUF)                                                      \
    {                                                                       \
        float2 ph = lph[(T) * 32 + zk];                                     \
        bf16x8 zr, zi;                                                      \
        _Pragma("unroll")                                                   \
        for (int j = 0; j < 8; j++) {                                       \
            int c_ = zcb * 8 + j;                                           \
            u32 xv = lxu[c_ * 32 +                                          \
                         (((zk >> 2) ^ j ^ zcb) << 2) + (zk & 3)];          \
            float xr = bf2f((u16)(xv & 0xffff));                            \
            float xi = bf2f((u16)(xv >> 16));                               \
            zr[j] = (short)f2bf(xr * ph.x - xi * ph.y);                     \
            zi[j] = (short)f2bf(xi * ph.x + xr * ph.y);                     \
        }                                                                   \
        int rR = 2 * zk, rI = 2 * zk + 1;                                   \
        *(bf16x8*)(lzc + (BUF)*8192 + rR * 128 + ((zcb ^ (rR & 7)) << 4)) = zr; \
        *(bf16x8*)(lzc + (BUF)*8192 + rI * 128 + ((zcb ^ (rI & 7)) << 4)) = zi; \
    }

#define STAGE_A2(T, BUF)                                                    \
    _Pragma("unroll")                                                       \
    for (int j = 0; j < 4; j++) {                                           \
        gload16(F2 + (size_t)(wid * 32 + j * 8 + (lane >> 3)) * 576 +       \
                    (T) * 64 + (((lane & 7) ^ (lane >> 3)) * 8),            \
                lac + (BUF)*16384 + (wid * 32 + j * 8) * 128);              \
    }

__global__ __launch_bounds__(256, 2) void step_c2(const u16* __restrict__ XF_,
                                                  const u16* __restrict__ F2,
                                                  const float2* __restrict__ PH,
                                                  u16* __restrict__ S) {
    __shared__ u16 la[2 * 128 * 64];    // 32 KB  A double-buffer
    __shared__ u16 lz[2 * 64 * 64];     // 16 KB  Z double-buffer
    __shared__ u32 lx[64 * 32];         // 8 KB   X tile (packed complex, swz)
    __shared__ float2 lph[TAPS * 32];   // 2.25 KB
    const int tid = threadIdx.x;
    const int lane = tid & 63, wid = tid >> 6;
    const int kt = blockIdx.x, n = blockIdx.y;
    const int fr = lane & 15;
    const int hk = (lane >> 4) << 4;
    const int askew = (fr & 7) << 4;
    char* lac = (char*)la;
    char* lzc = (char*)lz;
    char* lxc = (char*)lx;
    const u32* lxu = lx;
    const int zk = tid >> 3;            // 0..31 local bin
    const int zcb = tid & 7;            // c-block of 8

    // stage X tile: rows c = wid*16+j*8+(lane>>3), 16B col16 ^= (c&7)^(c>>3)
#pragma unroll
    for (int j = 0; j < 2; j++) {
        int c_ = wid * 16 + j * 8 + (lane >> 3);
        gload16(XF_ + (size_t)(n * 64 + c_) * MP1 + kt * 64 +
                    (((lane & 7) ^ (lane >> 3) ^ (wid * 2 + j)) * 8),
                lxc + (wid * 16 + j * 8) * 128);
    }
    // lph: 288 entries > 256 threads -> grid-stride (round-5 bug was `if`)
    for (int i = tid; i < TAPS * 32; i += 256) {
        int w_ = i >> 5, b_ = i & 31;
        lph[i] = PH[w_ * KB2 + kt * 32 + b_];
    }
    __syncthreads();

    f32x4 acc[2][4];
#pragma unroll
    for (int i = 0; i < 2; i++)
#pragma unroll
        for (int j = 0; j < 4; j++) acc[i][j] = (f32x4){0.f, 0.f, 0.f, 0.f};

    ZBUILD(0, 0)
    STAGE_A2(0, 0)
    __syncthreads();

    bf16x8 af[2][2], bfr[4][2];
    for (int t = 0; t < TAPS; ++t) {
        const int cur = t & 1, nxt = cur ^ 1;
#pragma unroll
        for (int m2 = 0; m2 < 2; m2++)
#pragma unroll
            for (int kk = 0; kk < 2; kk++) {
                int row_ = wid * 32 + m2 * 16 + fr;
                af[m2][kk] = *(const bf16x8*)(lac + cur * 16384 + row_ * 128 +
                                              ((kk * 64 + hk) ^ askew));
            }
#pragma unroll
        for (int n4 = 0; n4 < 4; n4++)
#pragma unroll
            for (int kk = 0; kk < 2; kk++) {
                int row_ = n4 * 16 + fr;
                bfr[n4][kk] = *(const bf16x8*)(lzc + cur * 8192 + row_ * 128 +
                                               ((kk * 64 + hk) ^ askew));
            }
        if (t + 1 < TAPS) {
            ZBUILD(t + 1, nxt)
            STAGE_A2(t + 1, nxt)
        }
        __builtin_amdgcn_s_setprio(1);
#pragma unroll
        for (int kk = 0; kk < 2; kk++)
#pragma unroll
            for (int m2 = 0; m2 < 2; m2++)
#pragma unroll
                for (int n4 = 0; n4 < 4; n4++)
                    acc[m2][n4] = __builtin_amdgcn_mfma_f32_16x16x32_bf16(
                        af[m2][kk], bfr[n4][kk], acc[m2][n4], 0, 0, 0);
        __builtin_amdgcn_s_setprio(0);
        __syncthreads();
    }

    // epilogue: S[n*128+f][kt*64+col], C/D layout col=lane&15,row=(lane>>4)*4+j
#pragma unroll
    for (int m2 = 0; m2 < 2; m2++) {
#pragma unroll
        for (int n4 = 0; n4 < 4; n4++) {
            int colk = kt * 64 + n4 * 16 + fr;
            int f0 = wid * 32 + m2 * 16 + ((lane >> 4) << 2);
#pragma unroll
            for (int j = 0; j < 4; j++) {
                int sig2 = n * 128 + f0 + j;
                S[(size_t)sig2 * KP + colk] = f2bf(acc[m2][n4][j]);
            }
        }
    }
}

// ---------- launch ----------
extern "C" void kernel_launch(void* const* d_in, const int* in_sizes, int n_in,
                              void* d_out, int out_size, void* d_ws, size_t ws_size,
                              hipStream_t stream) {
    (void)in_sizes; (void)n_in; (void)out_size; (void)ws_size;
    const float* x    = (const float*)d_in[0];
    const float* filt = (const float*)d_in[1];
    const float* bias = (const float*)d_in[2];

    char* ws = (char*)d_ws;
    u16* TT = (u16*)(ws);                  // 60,817,408 B (Ttab, then Dtab)
    u16* XF = (u16*)(ws + 60817408);       // 2048 x 7424 bf16 = 30,408,704
    u16* XB = (u16*)(ws + 91226112);       // 2048 x 4096 bf16 = 16,777,216
    u16* S  = (u16*)(ws + 108003328);      // 4096 x 7232 bf16 = 59,244,544
    u16* F2 = (u16*)(ws + 167247872);      // 128 x 576 bf16   = 147,456
    float2* PH = (float2*)(ws + 167395328); // 9 x 3616 float2 = 260,352
    // total: 167,655,680 B

    hipFuncSetAttribute(reinterpret_cast<const void*>(gemm256<0>),
                        hipFuncAttributeMaxDynamicSharedMemorySize, 131072);
    hipFuncSetAttribute(reinterpret_cast<const void*>(gemm256<1>),
                        hipFuncAttributeMaxDynamicSharedMemorySize, 131072);

    cast_x<<<4096, 256, 0, stream>>>(x, XB, NB * CC * WW_);
    gen_ph<<<(TAPS * KB2 + 255) / 256, 256, 0, stream>>>(PH);
    gen_filt2<<<(FF * 576 + 255) / 256, 256, 0, stream>>>(filt, F2);
    gen_ttab<<<MP1, 256, 0, stream>>>(TT);
    gemm256<0><<<8 * (MP1 / 256), 512, 131072, stream>>>(
        XB, TT, WW_, MP1 / 256, XF, MP1, nullptr);
    gen_dtab<<<SIG2, 256, 0, stream>>>(TT);   // overwrites Ttab (dead after G1)
    step_c2<<<dim3(KP / 64, NB), 256, 0, stream>>>(XF, F2, PH, S);
    gemm256<1><<<16 * 16, 512, 131072, stream>>>(
        S, TT, KP, 16, d_out, OW, bias);
}

// Round 7
// 432.195 us; speedup vs baseline: 2.0553x; 1.0595x over previous
//
#include <hip/hip_runtime.h>
#include <hip/hip_bf16.h>

typedef unsigned short u16;
typedef unsigned int   u32;

using bf16x8 = __attribute__((ext_vector_type(8))) short;
using f32x4  = __attribute__((ext_vector_type(4))) float;

// ---------- constants ----------
#define NB    32      // batch
#define CC    64      // in channels
#define WW_   4096    // input width
#define FF    128     // out channels
#define TAPS  9
#define NFFT  8192
#define KBINS 3597    // half_compressed
#define KB2   3616    // bins padded to 113*32 (PH table size)
#define N2    7194    // compress_fft_size
#define OW    4088    // out width
#define KP    7232    // padded 2*KBINS (mult of 64)
#define MP1   7424    // padded 2*KBINS cols for G1 (mult of 256)
#define SIG1  2048    // N*C
#define SIG2  4096    // N*F

__device__ __forceinline__ u16 f2bf(float f) {
    u32 u = __float_as_uint(f);
    return (u16)((u + 0x7FFFu + ((u >> 16) & 1u)) >> 16);
}
__device__ __forceinline__ float bf2f(u16 h) {
    return __uint_as_float(((u32)h) << 16);
}

// async global->LDS, 16B per lane; lds dest is wave-uniform base + lane*16
__device__ __forceinline__ void gload16(const void* g, void* l) {
    __builtin_amdgcn_global_load_lds(
        (const __attribute__((address_space(1))) void*)g,
        (__attribute__((address_space(3))) void*)l, 16, 0, 0);
}

// ---------- cast x to bf16 ----------
__global__ __launch_bounds__(256) void cast_x(const float* __restrict__ x,
                                              u16* __restrict__ xb, int n) {
    int stride = gridDim.x * blockDim.x;
    for (int i = blockIdx.x * blockDim.x + threadIdx.x; i < n; i += stride)
        xb[i] = f2bf(x[i]);
}

// ---------- Ttab[m][tau], m=2k(+1): cos / -sin of 2*pi*k*tau/8192 ----------
__global__ __launch_bounds__(256) void gen_ttab(u16* __restrict__ T) {
    int m = blockIdx.x;              // 0..MP1-1
    int k = m >> 1;
    u16* row = T + (size_t)m * WW_;
    for (int tau = threadIdx.x; tau < WW_; tau += 256) {
        float v = 0.f;
        if (k < KBINS && m < 2 * KBINS) {
            int r = (k * tau) & (NFFT - 1);   // exact integer phase
            float th = (float)r * (6.28318530717958647692f / (float)NFFT);
            float s, c;
            sincosf(th, &s, &c);
            v = (m & 1) ? -s : c;
        }
        row[tau] = f2bf(v);
    }
}

// ---------- Dtab[t][k2]: scaled cos / -sin of 2*pi*k*t/7194 ----------
__global__ __launch_bounds__(256) void gen_dtab(u16* __restrict__ D) {
    int t = blockIdx.x;              // 0..4095
    u16* row = D + (size_t)t * KP;
    for (int k2 = threadIdx.x; k2 < KP; k2 += 256) {
        int k = k2 >> 1;
        float v = 0.f;
        if (k < KBINS) {
            int r = (k * t) % N2;             // exact integer phase
            float th = (float)r * (6.28318530717958647692f / (float)N2);
            float s, c;
            sincosf(th, &s, &c);
            float sc = (k == 0) ? (1.0f / (float)N2) : (2.0f / (float)N2);
            v = (k2 & 1) ? (-s * sc) : (c * sc);
        }
        row[k2] = f2bf(v);
    }
}

// ---------- PH[w][b]: (cos,sin) of 2*pi*b*w/8192; 0 for b>=KBINS ----------
__global__ __launch_bounds__(256) void gen_ph(float2* __restrict__ PH) {
    int idx = blockIdx.x * 256 + threadIdx.x;
    if (idx >= TAPS * KB2) return;
    int w = idx / KB2, b = idx % KB2;
    float2 v = {0.f, 0.f};
    if (b < KBINS) {
        int r = (b * w) & (NFFT - 1);
        float th = (float)r * (6.28318530717958647692f / (float)NFFT);
        sincosf(th, &v.y, &v.x);
    }
    PH[idx] = v;
}

// ---------- filt2[f][w*64+c] = bf16(filt[f][c][w]) ----------
__global__ __launch_bounds__(256) void gen_filt2(const float* __restrict__ filt,
                                                 u16* __restrict__ F2) {
    int idx = blockIdx.x * 256 + threadIdx.x;
    if (idx >= FF * 576) return;
    int f = idx / 576, wc = idx % 576;
    int w = wc >> 6, c = wc & 63;
    F2[idx] = f2bf(filt[((size_t)f * CC + c) * TAPS + w]);
}

// ============ 256x256 MFMA GEMM, 2-barrier/K-tile register-pipelined =======
// out[m][n] = sum_k A[m][k]*BT[n][k]; 512 thr = 8 waves (2M x 4N); BK=64;
// LDS 128KB double-buffered. Per K-tile t (cur=t&1, nxt=cur^1):
//   LOAD a0,b0,b1 (cur); STAGE B(t+1)->nxt; q00 (a1 loads under its shadow);
//   q01; lgkmcnt(0); BAR#1; STAGE A(t+2)->cur (A region dead); q11; q10;
//   vmcnt(4) [A(t+2) stays in flight]; BAR#2.
// Invariant entering tile t: buffer cur fully staged, A(t+1) (4 loads)
// outstanding. Prologue establishes it; tails: t=NT-2 -> vmcnt(0).
#define MFMA_Q(AS, BS, MH, NH)                                              \
    __builtin_amdgcn_s_setprio(1);                                          \
    _Pragma("unroll")                                                       \
    for (int kk = 0; kk < 2; kk++)                                          \
        _Pragma("unroll")                                                   \
        for (int m4 = 0; m4 < 4; m4++)                                      \
            _Pragma("unroll")                                               \
            for (int n2 = 0; n2 < 2; n2++)                                  \
                acc[(MH)*4 + m4][(NH)*2 + n2] =                             \
                    __builtin_amdgcn_mfma_f32_16x16x32_bf16(                \
                        AS[m4][kk], BS[n2][kk],                             \
                        acc[(MH)*4 + m4][(NH)*2 + n2], 0, 0, 0);            \
    __builtin_amdgcn_s_setprio(0);

#define LOAD_A(AS, MH, BUF)                                                 \
    _Pragma("unroll")                                                       \
    for (int m4 = 0; m4 < 4; m4++)                                          \
        _Pragma("unroll")                                                   \
        for (int kk = 0; kk < 2; kk++) {                                    \
            int row_ = wr * 128 + (MH)*64 + m4 * 16 + fr;                   \
            AS[m4][kk] = *(const bf16x8*)(smem + (BUF)*32768 +              \
                          row_ * 128 + ((kk * 64 + hk) ^ askew));           \
        }

#define LOAD_B(BS, NH, BUF)                                                 \
    _Pragma("unroll")                                                       \
    for (int n2 = 0; n2 < 2; n2++)                                          \
        _Pragma("unroll")                                                   \
        for (int kk = 0; kk < 2; kk++) {                                    \
            int row_ = wc * 64 + (NH)*32 + n2 * 16 + fr;                    \
            BS[n2][kk] = *(const bf16x8*)(smem + 65536 + (BUF)*32768 +      \
                          row_ * 128 + ((kk * 64 + hk) ^ askew));           \
        }

#define STAGE(Q, R, BUF)                                                    \
    {                                                                       \
        const u16* g_ = ((R) < 2) ? gA : gB;                                \
        size_t ro_ = (size_t)((R)&1) * 128 * K;                             \
        int lb_ = (((R) < 2) ? 0 : 65536) + (BUF)*32768 +                   \
                  (((R)&1) * 128 + wid * 16) * 128;                         \
        gload16(g_ + ro_ + (Q)*64, smem + lb_);                             \
        gload16(g_ + ro_ + (size_t)8 * K + (Q)*64, smem + lb_ + 1024);      \
    }

#define BAR() __builtin_amdgcn_s_barrier()

template <int MODE>
__global__ __launch_bounds__(512, 1) void gemm256(const u16* __restrict__ A,
                                                  const u16* __restrict__ B,
                                                  int K, int gridN,
                                                  void* __restrict__ Out,
                                                  int ldo,
                                                  const float* __restrict__ bias) {
    extern __shared__ char smem[];   // [A b0|A b1|B b0|B b1] x 32KB
    const int tid = threadIdx.x;
    const int lane = tid & 63, wid = tid >> 6;
    const int wr = wid >> 2, wc = wid & 3;
    const int fr = lane & 15;
    const int hk = (lane >> 4) << 4;
    const int askew = (fr & 7) << 4;

    const int nwg = (int)gridDim.x, cpx = nwg >> 3;
    const int bid = (int)blockIdx.x;
    const int wg = (bid & 7) * cpx + (bid >> 3);
    const int tm = wg / gridN, tn = wg % gridN;
    const int NT = K >> 6;

    f32x4 acc[8][4];
#pragma unroll
    for (int i = 0; i < 8; i++)
#pragma unroll
        for (int j = 0; j < 4; j++) acc[i][j] = (f32x4){0.f, 0.f, 0.f, 0.f};

    const int srow = lane >> 3;
    const int scol = ((lane & 7) ^ srow) * 8;
    const u16* gA = A + (size_t)(tm * 256 + wid * 16 + srow) * K + scol;
    const u16* gB = B + (size_t)(tn * 256 + wid * 16 + srow) * K + scol;

    // prologue: full tile0 -> buf0, A(1) -> buf1; leaves A(1) in flight
    STAGE(0, 0, 0) STAGE(0, 1, 0) STAGE(0, 2, 0) STAGE(0, 3, 0)
    STAGE(1, 0, 1) STAGE(1, 1, 1)
    asm volatile("s_waitcnt vmcnt(4)" ::: "memory");
    BAR();

    bf16x8 a0[4][2], a1[4][2], b0[2][2], b1[2][2];
    for (int t = 0; t < NT; ++t) {
        const int cur = t & 1, nxt = cur ^ 1;
        LOAD_A(a0, 0, cur)
        LOAD_B(b0, 0, cur)
        LOAD_B(b1, 1, cur)
        if (t + 1 < NT) { STAGE(t + 1, 2, nxt) STAGE(t + 1, 3, nxt) }
        MFMA_Q(a0, b0, 0, 0)
        LOAD_A(a1, 1, cur)          // issued under q01's MFMA shadow
        MFMA_Q(a0, b1, 0, 1)
        asm volatile("s_waitcnt lgkmcnt(0)" ::: "memory");  // cur-A reads done
        __builtin_amdgcn_sched_barrier(0);
        BAR();                       // #1: cur-A region now dead block-wide
        if (t + 2 < NT) { STAGE(t + 2, 0, cur) STAGE(t + 2, 1, cur) }
        MFMA_Q(a1, b1, 1, 1)
        MFMA_Q(a1, b0, 1, 0)
        if (t + 2 < NT) {
            asm volatile("s_waitcnt vmcnt(4)" ::: "memory");  // A(t+1),B(t+1) in
        } else if (t + 1 < NT) {
            asm volatile("s_waitcnt vmcnt(0)" ::: "memory");  // drain for last
        }
        BAR();                       // #2: publish nxt
    }

    // epilogue: C/D frag layout col=lane&15, row=(lane>>4)*4+j  [m89]
#pragma unroll
    for (int m = 0; m < 8; m++) {
#pragma unroll
        for (int n = 0; n < 4; n++) {
            int col  = tn * 256 + wc * 64 + n * 16 + fr;
            int row0 = tm * 256 + wr * 128 + m * 16 + ((lane >> 4) << 2);
#pragma unroll
            for (int j = 0; j < 4; j++) {
                int grow = row0 + j;
                if (MODE == 0) {
                    ((u16*)Out)[(size_t)grow * ldo + col] = f2bf(acc[m][n][j]);
                } else {
                    if (col < OW) {
                        ((float*)Out)[(size_t)grow * OW + col] =
                            acc[m][n][j] + bias[grow & 127];
                    }
                }
            }
        }
    }
}

// ============ step_c2: spectral contraction as one MFMA GEMM over (c,w) ====
// spec[n,f,k] = sum_{c,w} filt[f,c,w] * (X[n,c,k] * e^{i*2pi*k*w/8192})
// A = filt2[f][w*64+c] (128x576 bf16); B = Z tile built in LDS per K-step
// (step t == tap w=t). Block: (kt: 64 k2-cols = 32 bins, n). 256 thr, 4 waves.
#define ZBUILD(T, BUF)                                                      \
    {                                                                       \
        float2 ph = lph[(T) * 32 + zk];                                     \
        bf16x8 zr, zi;                                                      \
        _Pragma("unroll")                                                   \
        for (int j = 0; j < 8; j++) {                                       \
            int c_ = zcb * 8 + j;                                           \
            u32 xv = lxu[c_ * 32 +                                          \
                         (((zk >> 2) ^ j ^ zcb) << 2) + (zk & 3)];          \
            float xr = bf2f((u16)(xv & 0xffff));                            \
            float xi = bf2f((u16)(xv >> 16));                               \
            zr[j] = (short)f2bf(xr * ph.x - xi * ph.y);                     \
            zi[j] = (short)f2bf(xi * ph.x + xr * ph.y);                     \
        }                                                                   \
        int rR = 2 * zk, rI = 2 * zk + 1;                                   \
        *(bf16x8*)(lzc + (BUF)*8192 + rR * 128 + ((zcb ^ (rR & 7)) << 4)) = zr; \
        *(bf16x8*)(lzc + (BUF)*8192 + rI * 128 + ((zcb ^ (rI & 7)) << 4)) = zi; \
    }

#define STAGE_A2(T, BUF)                                                    \
    _Pragma("unroll")                                                       \
    for (int j = 0; j < 4; j++) {                                           \
        gload16(F2 + (size_t)(wid * 32 + j * 8 + (lane >> 3)) * 576 +       \
                    (T) * 64 + (((lane & 7) ^ (lane >> 3)) * 8),            \
                lac + (BUF)*16384 + (wid * 32 + j * 8) * 128);              \
    }

__global__ __launch_bounds__(256, 2) void step_c2(const u16* __restrict__ XF_,
                                                  const u16* __restrict__ F2,
                                                  const float2* __restrict__ PH,
                                                  u16* __restrict__ S) {
    __shared__ u16 la[2 * 128 * 64];    // 32 KB  A double-buffer
    __shared__ u16 lz[2 * 64 * 64];     // 16 KB  Z double-buffer
    __shared__ u32 lx[64 * 32];         // 8 KB   X tile (packed complex, swz)
    __shared__ float2 lph[TAPS * 32];   // 2.25 KB
    const int tid = threadIdx.x;
    const int lane = tid & 63, wid = tid >> 6;
    const int kt = blockIdx.x, n = blockIdx.y;
    const int fr = lane & 15;
    const int hk = (lane >> 4) << 4;
    const int askew = (fr & 7) << 4;
    char* lac = (char*)la;
    char* lzc = (char*)lz;
    char* lxc = (char*)lx;
    const u32* lxu = lx;
    const int zk = tid >> 3;            // 0..31 local bin
    const int zcb = tid & 7;            // c-block of 8

    // stage X tile: rows c = wid*16+j*8+(lane>>3), 16B col16 ^= (c&7)^(c>>3)
#pragma unroll
    for (int j = 0; j < 2; j++) {
        int c_ = wid * 16 + j * 8 + (lane >> 3);
        gload16(XF_ + (size_t)(n * 64 + c_) * MP1 + kt * 64 +
                    (((lane & 7) ^ (lane >> 3) ^ (wid * 2 + j)) * 8),
                lxc + (wid * 16 + j * 8) * 128);
    }
    // lph: 288 entries > 256 threads -> grid-stride
    for (int i = tid; i < TAPS * 32; i += 256) {
        int w_ = i >> 5, b_ = i & 31;
        lph[i] = PH[w_ * KB2 + kt * 32 + b_];
    }
    __syncthreads();

    f32x4 acc[2][4];
#pragma unroll
    for (int i = 0; i < 2; i++)
#pragma unroll
        for (int j = 0; j < 4; j++) acc[i][j] = (f32x4){0.f, 0.f, 0.f, 0.f};

    ZBUILD(0, 0)
    STAGE_A2(0, 0)
    __syncthreads();

    bf16x8 af[2][2], bfr[4][2];
    for (int t = 0; t < TAPS; ++t) {
        const int cur = t & 1, nxt = cur ^ 1;
#pragma unroll
        for (int m2 = 0; m2 < 2; m2++)
#pragma unroll
            for (int kk = 0; kk < 2; kk++) {
                int row_ = wid * 32 + m2 * 16 + fr;
                af[m2][kk] = *(const bf16x8*)(lac + cur * 16384 + row_ * 128 +
                                              ((kk * 64 + hk) ^ askew));
            }
#pragma unroll
        for (int n4 = 0; n4 < 4; n4++)
#pragma unroll
            for (int kk = 0; kk < 2; kk++) {
                int row_ = n4 * 16 + fr;
                bfr[n4][kk] = *(const bf16x8*)(lzc + cur * 8192 + row_ * 128 +
                                               ((kk * 64 + hk) ^ askew));
            }
        if (t + 1 < TAPS) {
            ZBUILD(t + 1, nxt)
            STAGE_A2(t + 1, nxt)
        }
        __builtin_amdgcn_s_setprio(1);
#pragma unroll
        for (int kk = 0; kk < 2; kk++)
#pragma unroll
            for (int m2 = 0; m2 < 2; m2++)
#pragma unroll
                for (int n4 = 0; n4 < 4; n4++)
                    acc[m2][n4] = __builtin_amdgcn_mfma_f32_16x16x32_bf16(
                        af[m2][kk], bfr[n4][kk], acc[m2][n4], 0, 0, 0);
        __builtin_amdgcn_s_setprio(0);
        __syncthreads();
    }

    // epilogue: S[n*128+f][kt*64+col], C/D layout col=lane&15,row=(lane>>4)*4+j
#pragma unroll
    for (int m2 = 0; m2 < 2; m2++) {
#pragma unroll
        for (int n4 = 0; n4 < 4; n4++) {
            int colk = kt * 64 + n4 * 16 + fr;
            int f0 = wid * 32 + m2 * 16 + ((lane >> 4) << 2);
#pragma unroll
            for (int j = 0; j < 4; j++) {
                int sig2 = n * 128 + f0 + j;
                S[(size_t)sig2 * KP + colk] = f2bf(acc[m2][n4][j]);
            }
        }
    }
}

// ---------- launch ----------
extern "C" void kernel_launch(void* const* d_in, const int* in_sizes, int n_in,
                              void* d_out, int out_size, void* d_ws, size_t ws_size,
                              hipStream_t stream) {
    (void)in_sizes; (void)n_in; (void)out_size; (void)ws_size;
    const float* x    = (const float*)d_in[0];
    const float* filt = (const float*)d_in[1];
    const float* bias = (const float*)d_in[2];

    char* ws = (char*)d_ws;
    u16* TT = (u16*)(ws);                  // 60,817,408 B (Ttab, then Dtab)
    u16* XF = (u16*)(ws + 60817408);       // 2048 x 7424 bf16 = 30,408,704
    u16* XB = (u16*)(ws + 91226112);       // 2048 x 4096 bf16 = 16,777,216
    u16* S  = (u16*)(ws + 108003328);      // 4096 x 7232 bf16 = 59,244,544
    u16* F2 = (u16*)(ws + 167247872);      // 128 x 576 bf16   = 147,456
    float2* PH = (float2*)(ws + 167395328); // 9 x 3616 float2 = 260,352
    // total: 167,655,680 B

    hipFuncSetAttribute(reinterpret_cast<const void*>(gemm256<0>),
                        hipFuncAttributeMaxDynamicSharedMemorySize, 131072);
    hipFuncSetAttribute(reinterpret_cast<const void*>(gemm256<1>),
                        hipFuncAttributeMaxDynamicSharedMemorySize, 131072);

    cast_x<<<4096, 256, 0, stream>>>(x, XB, NB * CC * WW_);
    gen_ph<<<(TAPS * KB2 + 255) / 256, 256, 0, stream>>>(PH);
    gen_filt2<<<(FF * 576 + 255) / 256, 256, 0, stream>>>(filt, F2);
    gen_ttab<<<MP1, 256, 0, stream>>>(TT);
    gemm256<0><<<8 * (MP1 / 256), 512, 131072, stream>>>(
        XB, TT, WW_, MP1 / 256, XF, MP1, nullptr);
    gen_dtab<<<SIG2, 256, 0, stream>>>(TT);   // overwrites Ttab (dead after G1)
    step_c2<<<dim3(KP / 64, NB), 256, 0, stream>>>(XF, F2, PH, S);
    gemm256<1><<<16 * 16, 512, 131072, stream>>>(
        S, TT, KP, 16, d_out, OW, bias);
}